// Round 13
// baseline (209.712 us; speedup 1.0000x reference)
//
#include <hip/hip_runtime.h>
#include <hip/hip_bf16.h>
#include <stdint.h>

typedef __bf16 bf16;
typedef __bf16 bf16x2 __attribute__((ext_vector_type(2)));
typedef __bf16 bf16x4 __attribute__((ext_vector_type(4)));
typedef __bf16 bf16x8 __attribute__((ext_vector_type(8)));
typedef float  f32x4  __attribute__((ext_vector_type(4)));

#define BATCH 4
#define SEQ 2048
#define DM 1024
#define NH 16
#define HD 64
#define M_TOT (BATCH*SEQ)   // 8192
#define QKV_N (3*DM)        // 3072

#if __has_builtin(__builtin_amdgcn_exp2f)
#define EXP2F(x) __builtin_amdgcn_exp2f(x)
#else
#define EXP2F(x) exp2f(x)
#endif
#if __has_builtin(__builtin_amdgcn_rcpf)
#define RCPF(x) __builtin_amdgcn_rcpf(x)
#else
#define RCPF(x) (1.0f/(x))
#endif

__device__ __forceinline__ void gld_lds16(const bf16* g, bf16* l) {
    __builtin_amdgcn_global_load_lds(
        (const __attribute__((address_space(1))) void*)g,
        (__attribute__((address_space(3))) void*)l, 16, 0, 0);
}

// ---------------- fused fp32 -> bf16 converts (one launch) ----------------
__device__ __forceinline__ void cvt_seg(const float* __restrict__ src,
                                        bf16* __restrict__ dst,
                                        int n, int tid0, int nthreads) {
    for (int idx = tid0 * 8; idx < n; idx += nthreads * 8) {
        float4 a = *(const float4*)(src + idx);
        float4 b = *(const float4*)(src + idx + 4);
        bf16x8 o;
        o[0] = (bf16)a.x; o[1] = (bf16)a.y; o[2] = (bf16)a.z; o[3] = (bf16)a.w;
        o[4] = (bf16)b.x; o[5] = (bf16)b.y; o[6] = (bf16)b.z; o[7] = (bf16)b.w;
        *(bf16x8*)(dst + idx) = o;
    }
}

__global__ void cvt3_kernel(const float* __restrict__ x, bf16* __restrict__ xb,
                            const float* __restrict__ w1, bf16* __restrict__ w1b,
                            const float* __restrict__ w2, bf16* __restrict__ w2b) {
    int bid = blockIdx.x, tid = threadIdx.x;
    if (bid < 1024)       cvt_seg(x,  xb,  M_TOT * DM,  bid * 256 + tid,          1024 * 256);
    else if (bid < 1280)  cvt_seg(w1, w1b, QKV_N * DM, (bid - 1024) * 256 + tid,  256 * 256);
    else                  cvt_seg(w2, w2b, DM * DM,    (bid - 1280) * 256 + tid,  128 * 256);
}

#define SB()    __builtin_amdgcn_s_barrier()
#define MEMF()  asm volatile("" ::: "memory")
#define LGKM0() asm volatile("s_waitcnt lgkmcnt(0)" ::: "memory")
#define VMCNT0() asm volatile("s_waitcnt vmcnt(0)" ::: "memory")
#define FRAG(buf, row, ks) (*(const bf16x8*)&(buf)[(int)(row) * 64 + ((((ks) << 2) + g) ^ l7) * 8])

// ---------------- GEMM1: 256x384 tiles, 256 blocks = exactly 1/CU, no tail ----
// BM=256 BN=384 BK=64, 8 waves (2M x 4N), wave tile 128x96 (MREP=8, NREP=6).
// LDS 160KB: As[2][256][64] + Bs[2][384][64]. acc[8][6] f32x4 = 192 VGPR.
// R12 BUGFIX: a wave's B reads are COLUMN slices (rB=wcn*96) that span all
// three 128-row stage units, so per-unit early staging (P2/P3) raced with
// other waves' reads (wcn=0 read unit-0 rows 64..95 at P4 after P2 overwrote
// them). Fix: ALL B(t+2) units staged at P5 — every B read retires by P4's
// end barrier. vmcnt(6) at P5 = newest 3 stages (6 loads) in flight; A(t+1)
// and B(t+1) forced complete. B(t) completeness enforced by tile t-1's vmcnt.
#define RDA(AF, CA) \
    _Pragma("unroll") for (int i = 0; i < 2; i++) \
        _Pragma("unroll") for (int ks = 0; ks < 2; ks++) \
            AF[i][ks] = FRAG(Ap, rA + ((CA) * 2 + i) * 16 + q, ks);
#define RDB(CB) \
    _Pragma("unroll") for (int n = 0; n < 2; n++) \
        _Pragma("unroll") for (int ks = 0; ks < 2; ks++) \
            bfra[n][ks] = FRAG(Bp, rB + ((CB) * 2 + n) * 16 + q, ks);
#define MMPAIR(AF, CA, CB) \
    _Pragma("unroll") for (int i = 0; i < 2; i++) \
        _Pragma("unroll") for (int n = 0; n < 2; n++) \
            _Pragma("unroll") for (int ks = 0; ks < 2; ks++) \
                acc[(CA) * 2 + i][(CB) * 2 + n] = __builtin_amdgcn_mfma_f32_16x16x32_bf16( \
                    AF[i][ks], bfra[n][ks], acc[(CA) * 2 + i][(CB) * 2 + n], 0, 0, 0);

__global__ __launch_bounds__(512, 2) void gemm1_384(
    const bf16* __restrict__ A, const bf16* __restrict__ B,
    const float* __restrict__ bias, bf16* __restrict__ C,
    int M, int N, int K)
{
    extern __shared__ __align__(16) bf16 lds[];
    bf16* As = lds;                    // [2][256][64]
    bf16* Bs = lds + 2 * 256 * 64;     // [2][384][64]

    const int tid = threadIdx.x, wid = tid >> 6, lane = tid & 63;
    const int q = lane & 15, g = lane >> 4, l7 = lane & 7;
    const int wr = wid >> 2, wcn = wid & 3;   // 2M x 4N

    const int ntx = N / 384;
    const int nwg = gridDim.x * gridDim.y;
    const int bid = blockIdx.x + blockIdx.y * gridDim.x;
    const int wgid = (bid & 7) * (nwg >> 3) + (bid >> 3);   // nwg=256, %8==0
    const size_t rowbase = (size_t)(wgid / ntx) * 256;
    const size_t colbase = (size_t)(wgid % ntx) * 384;
    const int NT = K >> 6;
    const int rA = wr * 128;
    const int rB = wcn * 96;

    const bf16* Asrc = A + rowbase * K;
    const bf16* Bsrc = B + colbase * K;

    auto stage = [&](const bf16* src, bf16* dst) {
#pragma unroll
        for (int i = 0; i < 2; i++) {
            const int chunk = i * 8 + wid;            // 0..15, 8 rows each
            const int row = chunk * 8 + (lane >> 3);  // 0..127
            const int cg = (lane & 7) ^ (row & 7);
            gld_lds16(src + (size_t)row * K + cg * 8, dst + chunk * 512);
        }
    };

    // ---------------- prologue: tile0 full (B 3 units + A 2), tile1 B full ----
    stage(Bsrc,                   Bs);            // B0(0)
    stage(Bsrc + 128 * (size_t)K, Bs + 8192);     // B1(0)
    stage(Bsrc + 256 * (size_t)K, Bs + 16384);    // B2(0)
    stage(Asrc,                   As);            // A-h0(0)
    stage(Asrc + 128 * (size_t)K, As + 8192);     // A-h1(0)
    if (NT > 1) {
        stage(Bsrc + 64,                   Bs + 24576);          // B0(1)
        stage(Bsrc + 128 * (size_t)K + 64, Bs + 24576 + 8192);   // B1(1)
        stage(Bsrc + 256 * (size_t)K + 64, Bs + 24576 + 16384);  // B2(1)
        asm volatile("s_waitcnt vmcnt(6)" ::: "memory");  // tile0 complete
    } else {
        VMCNT0();
    }
    SB(); MEMF();

    f32x4 acc[8][6];
#pragma unroll
    for (int i = 0; i < 8; i++)
#pragma unroll
        for (int n = 0; n < 6; n++) acc[i][n] = (f32x4){0.f, 0.f, 0.f, 0.f};

    bf16x8 afa[2][2], afb[2][2], bfra[2][2];

    for (int t = 0; t < NT; t++) {
        const int p = t & 1;
        const bf16* Ap = As + p * 16384;
        const bf16* Bp = Bs + p * 24576;
        bf16* An  = As + (p ^ 1) * 16384;   // A dest for tile t+1
        bf16* Bn2 = Bs + p * 24576;         // B dest for tile t+2 (same parity)

        // ---- P0: read A0,A1,B0; stage A-h0(t+1) ----
        if (t + 1 < NT) stage(Asrc + (size_t)(t + 1) * 64, An);
        RDA(afa, 0) RDA(afb, 1) RDB(0)
        SB(); LGKM0();
        __builtin_amdgcn_s_setprio(1);
        MMPAIR(afa, 0, 0) MMPAIR(afb, 1, 0)
        __builtin_amdgcn_s_setprio(0);
        SB(); MEMF();

        // ---- P1: read A2,A3; stage A-h1(t+1) ----
        if (t + 1 < NT) stage(Asrc + 128 * (size_t)K + (size_t)(t + 1) * 64, An + 8192);
        RDA(afa, 2) RDA(afb, 3)
        SB(); LGKM0();
        __builtin_amdgcn_s_setprio(1);
        MMPAIR(afa, 2, 0) MMPAIR(afb, 3, 0)
        __builtin_amdgcn_s_setprio(0);
        SB(); MEMF();

        // ---- P2: read B1; no stage ----
        RDB(1)
        SB(); LGKM0();
        __builtin_amdgcn_s_setprio(1);
        MMPAIR(afa, 2, 1) MMPAIR(afb, 3, 1)
        __builtin_amdgcn_s_setprio(0);
        SB(); MEMF();

        // ---- P3: read A0,A1; no stage ----
        RDA(afa, 0) RDA(afb, 1)
        SB(); LGKM0();
        __builtin_amdgcn_s_setprio(1);
        MMPAIR(afa, 0, 1) MMPAIR(afb, 1, 1)
        __builtin_amdgcn_s_setprio(0);
        SB(); MEMF();

        // ---- P4: read B2 (last B read of the tile); no stage ----
        RDB(2)
        SB(); LGKM0();
        __builtin_amdgcn_s_setprio(1);
        MMPAIR(afa, 0, 2) MMPAIR(afb, 1, 2)
        __builtin_amdgcn_s_setprio(0);
        SB(); MEMF();

        // ---- P5: read A2,A3; stage ALL B(t+2) units (all B reads retired by
        //      P4-end barrier: every wave's column slice spans all 3 units) ----
        if (t + 2 < NT) {
            stage(Bsrc + (size_t)(t + 2) * 64,                   Bn2);
            stage(Bsrc + 128 * (size_t)K + (size_t)(t + 2) * 64, Bn2 + 8192);
            stage(Bsrc + 256 * (size_t)K + (size_t)(t + 2) * 64, Bn2 + 16384);
        }
        RDA(afa, 2) RDA(afb, 3)
        SB(); LGKM0();
        __builtin_amdgcn_s_setprio(1);
        MMPAIR(afa, 2, 2) MMPAIR(afb, 3, 2)
        __builtin_amdgcn_s_setprio(0);
        if (t + 2 < NT) { asm volatile("s_waitcnt vmcnt(6)" ::: "memory"); }
        else            { VMCNT0(); }
        SB(); MEMF();
    }

    // ---------------- epilogue ----------------
    float bv[6];
#pragma unroll
    for (int n = 0; n < 6; n++) bv[n] = bias[colbase + rB + n * 16 + q];
#pragma unroll
    for (int mi = 0; mi < 8; mi++) {
#pragma unroll
        for (int n = 0; n < 6; n++) {
            const size_t col = colbase + rB + n * 16 + q;
#pragma unroll
            for (int j = 0; j < 4; j++) {
                const size_t row = rowbase + rA + mi * 16 + g * 4 + j;
                C[row * N + col] = (bf16)(acc[mi][n][j] + bv[n]);
            }
        }
    }
}

// ---------------- 8-phase GEMM template (GEMM2: MREP=4, verified) ----------------
template<int MREP, int BF16_OUT>
__global__ __launch_bounds__(512, 2) void gemm8p_kernel(
    const bf16* __restrict__ A, const bf16* __restrict__ B,
    const float* __restrict__ bias, void* __restrict__ Cv,
    int M, int N, int K)
{
    constexpr int BM = MREP * 32;     // 256 or 128
    constexpr int AH = MREP / 2;      // frag-rows per A read phase
    extern __shared__ __align__(16) bf16 lds[];
    bf16* As = lds;                   // [2][BM][64]
    bf16* Bs = lds + 2 * BM * 64;     // [2][256][64]

    const int tid = threadIdx.x, wid = tid >> 6, lane = tid & 63;
    const int q = lane & 15, g = lane >> 4, l7 = lane & 7;
    const int wr = wid >> 2, wcn = wid & 3;

    const int ntx = N >> 8;
    const int nwg = gridDim.x * gridDim.y;
    const int bid = blockIdx.x + blockIdx.y * gridDim.x;
    const int wgid = (bid & 7) * (nwg >> 3) + (bid >> 3);   // grids are %8==0
    const size_t rowbase = (size_t)(wgid / ntx) * BM;
    const size_t colbase = (size_t)(wgid % ntx) * 256;
    const int NT = K >> 6;
    const int rA = wr * (MREP * 16);
    const int rB = wcn * 64;

    const bf16* Asrc = A + rowbase * K;
    const bf16* Bsrc = B + colbase * K;

    auto stage = [&](const bf16* src, bf16* dst) {
#pragma unroll
        for (int i = 0; i < 2; i++) {
            const int chunk = i * 8 + wid;            // 0..15, 8 rows each
            const int row = chunk * 8 + (lane >> 3);  // 0..127
            const int cg = (lane & 7) ^ (row & 7);
            gld_lds16(src + (size_t)row * K + cg * 8, dst + chunk * 512);
        }
    };

    // ---------------- prologue: tile0 (A+B) and tile1 (B halves) ----------------
    stage(Bsrc, Bs);                                         // B-h0(0)
    stage(Bsrc + 128 * (size_t)K, Bs + 8192);                // B-h1(0)
    stage(Asrc, As);                                         // A-h0(0)
    if (MREP == 8) stage(Asrc + 128 * (size_t)K, As + 8192); // A-h1(0)
    if (NT > 1) {
        stage(Bsrc + 64, Bs + 16384);                        // B-h0(1) -> buf1
        stage(Bsrc + 128 * (size_t)K + 64, Bs + 16384 + 8192);
        asm volatile("s_waitcnt vmcnt(4)" ::: "memory");     // tile0 complete
    } else {
        VMCNT0();
    }
    SB(); MEMF();

    f32x4 acc[MREP][4];
#pragma unroll
    for (int i = 0; i < MREP; i++)
#pragma unroll
        for (int n = 0; n < 4; n++) acc[i][n] = (f32x4){0.f, 0.f, 0.f, 0.f};

    bf16x8 af[AH][2], bfr[4][2];

    for (int t = 0; t < NT; t++) {
        const int p = t & 1;
        const bf16* Ap = As + p * (BM * 64);
        const bf16* Bp = Bs + p * 16384;
        bf16* An  = As + (p ^ 1) * (BM * 64);   // A dest for tile t+1
        bf16* Bn2 = Bs + p * 16384;             // B dest for tile t+2 (same parity)

        // ---------- P0: read A-half0 + B ni0-1; stage A-h0(t+1) ----------
        if (t + 1 < NT) stage(Asrc + (size_t)(t + 1) * 64, An);
#pragma unroll
        for (int i = 0; i < AH; i++) {
            const int row = rA + i * 16 + q;
#pragma unroll
            for (int ks = 0; ks < 2; ks++) af[i][ks] = FRAG(Ap, row, ks);
        }
#pragma unroll
        for (int n = 0; n < 2; n++) {
            const int row = rB + n * 16 + q;
#pragma unroll
            for (int ks = 0; ks < 2; ks++) bfr[n][ks] = FRAG(Bp, row, ks);
        }
        SB(); LGKM0();
        __builtin_amdgcn_s_setprio(1);
#pragma unroll
        for (int i = 0; i < AH; i++)
#pragma unroll
            for (int n = 0; n < 2; n++)
#pragma unroll
                for (int ks = 0; ks < 2; ks++)
                    acc[i][n] = __builtin_amdgcn_mfma_f32_16x16x32_bf16(af[i][ks], bfr[n][ks], acc[i][n], 0, 0, 0);
        __builtin_amdgcn_s_setprio(0);
        SB(); MEMF();

        // ---------- P1: read B ni2-3; stage A-h1(t+1) ----------
        if (MREP == 8 && t + 1 < NT)
            stage(Asrc + 128 * (size_t)K + (size_t)(t + 1) * 64, An + 8192);
#pragma unroll
        for (int n = 2; n < 4; n++) {
            const int row = rB + n * 16 + q;
#pragma unroll
            for (int ks = 0; ks < 2; ks++) bfr[n][ks] = FRAG(Bp, row, ks);
        }
        SB(); LGKM0();
        __builtin_amdgcn_s_setprio(1);
#pragma unroll
        for (int i = 0; i < AH; i++)
#pragma unroll
            for (int n = 2; n < 4; n++)
#pragma unroll
                for (int ks = 0; ks < 2; ks++)
                    acc[i][n] = __builtin_amdgcn_mfma_f32_16x16x32_bf16(af[i][ks], bfr[n][ks], acc[i][n], 0, 0, 0);
        __builtin_amdgcn_s_setprio(0);
        SB(); MEMF();

        // ---------- P2: read A-half1; stage B-h0(t+2) ----------
        if (t + 2 < NT) stage(Bsrc + (size_t)(t + 2) * 64, Bn2);
#pragma unroll
        for (int i = 0; i < AH; i++) {
            const int row = rA + (AH + i) * 16 + q;
#pragma unroll
            for (int ks = 0; ks < 2; ks++) af[i][ks] = FRAG(Ap, row, ks);
        }
        SB(); LGKM0();
        __builtin_amdgcn_s_setprio(1);
#pragma unroll
        for (int i = 0; i < AH; i++)
#pragma unroll
            for (int n = 2; n < 4; n++)
#pragma unroll
                for (int ks = 0; ks < 2; ks++)
                    acc[AH + i][n] = __builtin_amdgcn_mfma_f32_16x16x32_bf16(af[i][ks], bfr[n][ks], acc[AH + i][n], 0, 0, 0);
        __builtin_amdgcn_s_setprio(0);
        SB(); MEMF();

        // ---------- P3: no reads; stage B-h1(t+2); counted vmcnt ----------
        if (t + 2 < NT)
            stage(Bsrc + 128 * (size_t)K + (size_t)(t + 2) * 64, Bn2 + 8192);
        SB(); LGKM0();
        __builtin_amdgcn_s_setprio(1);
#pragma unroll
        for (int i = 0; i < AH; i++)
#pragma unroll
            for (int n = 0; n < 2; n++)
#pragma unroll
                for (int ks = 0; ks < 2; ks++)
                    acc[AH + i][n] = __builtin_amdgcn_mfma_f32_16x16x32_bf16(af[i][ks], bfr[n][ks], acc[AH + i][n], 0, 0, 0);
        __builtin_amdgcn_s_setprio(0);
        if (t + 2 < NT) { asm volatile("s_waitcnt vmcnt(4)" ::: "memory"); }
        else            { VMCNT0(); }
        SB(); MEMF();
    }

    // ---------------- epilogue ----------------
    float bv[4];
#pragma unroll
    for (int n = 0; n < 4; n++) bv[n] = bias[colbase + rB + n * 16 + q];
#pragma unroll
    for (int mi = 0; mi < MREP; mi++) {
#pragma unroll
        for (int n = 0; n < 4; n++) {
            const size_t col = colbase + rB + n * 16 + q;
#pragma unroll
            for (int j = 0; j < 4; j++) {
                const size_t row = rowbase + rA + mi * 16 + g * 4 + j;
                float v = acc[mi][n][j] + bv[n];
                if (BF16_OUT) ((bf16*)Cv)[row * N + col] = (bf16)v;
                else          ((float*)Cv)[row * N + col] = v;
            }
        }
    }
}

// ---------------- Flash attention v10 (R11-verified best: 85.8-86.4us) --------
// R5 Psm path + V-dbuf, ONE barrier per tile.
__global__ __launch_bounds__(256, 2) void attn_kernel(
    const bf16* __restrict__ qkv, bf16* __restrict__ attnout)
{
    __shared__ __align__(16) bf16 Ksm[2][64 * 64];
    __shared__ __align__(16) bf16 Vts[2][64 * 64];
    __shared__ __align__(16) bf16 Psm[4 * 64 * 64];

    const int tid = threadIdx.x, wid = tid >> 6, lane = tid & 63;
    const int g = lane >> 4, q = lane & 15, l7 = lane & 7;

    // bijective XCD swizzle: each XCD owns 8 consecutive bh (KV fits its L2)
    const int bid = blockIdx.x + blockIdx.y * gridDim.x;   // 0..511
    const int xcd = bid & 7, idx = bid >> 3;               // idx 0..63
    const int bh = xcd * 8 + (idx >> 3);
    const int qb = idx & 7;                                // 8 q-blocks of 256 rows
    const int b = bh >> 4, hh = bh & 15;

    const size_t rs = QKV_N;
    const bf16* qsec = qkv + (size_t)(b * SEQ) * rs + hh * 64;
    const bf16* ksec = qsec + DM;
    const bf16* vsec = qsec + 2 * DM;

    const float SC2 = 0.18033688011112042f;   // 0.125 * log2(e)

    // Q fragments pre-scaled into exp2 domain: 4 x 16 rows per wave
    bf16x8 qf[4][2];   // [qm][ks]
#pragma unroll
    for (int qm = 0; qm < 4; qm++) {
        int qrow = qb * 256 + wid * 64 + qm * 16 + q;
#pragma unroll
        for (int ks = 0; ks < 2; ks++) {
            bf16x8 raw = *(const bf16x8*)(qsec + (size_t)qrow * rs + ks * 32 + g * 8);
            bf16x8 sc;
#pragma unroll
            for (int j = 0; j < 8; j++) sc[j] = (bf16)((float)raw[j] * SC2);
            qf[qm][ks] = sc;
        }
    }

    bf16x8 onesf;
#pragma unroll
    for (int j = 0; j < 8; j++) onesf[j] = (bf16)1.0f;

    f32x4 acc[4][4];
    f32x4 acc_l[4];
#pragma unroll
    for (int qm = 0; qm < 4; qm++) {
        acc_l[qm] = (f32x4){0.f, 0.f, 0.f, 0.f};
#pragma unroll
        for (int dn = 0; dn < 4; dn++) acc[qm][dn] = (f32x4){0.f, 0.f, 0.f, 0.f};
    }
    bf16* Pw = &Psm[wid * 64 * 64];

    // V staging task: 2 keys x 8 d per thread
    const int vkey = 2 * (tid & 31);
    const int vd0 = (tid >> 5) * 8;

    // K tile staging: async global->LDS, source pre-swizzled (LDS-only lambda)
    auto stageK = [&](int kt, bf16* dst) {
#pragma unroll
        for (int r = 0; r < 2; r++) {
            int row = r * 32 + wid * 8 + (lane >> 3);
            int cbs = (lane & 7) ^ (row & 7);
            gld_lds16(ksec + (size_t)(kt + row) * rs + cbs * 8,
                      dst + (r * 32 + wid * 8) * 64);
        }
    };

    // ---------------- prologue: K(0)->Ksm[0], V(0)->Vts[0], V(1)->regs --------
    stageK(0, Ksm[0]);
    bf16x8 v0 = *(const bf16x8*)(vsec + (size_t)vkey * rs + vd0);
    bf16x8 v1 = *(const bf16x8*)(vsec + (size_t)(vkey + 1) * rs + vd0);
    VMCNT0();                       // K(0) in LDS, V(0) in regs
#pragma unroll
    for (int j = 0; j < 8; j++) {
        int pp = (vkey >> 3) ^ j;
        bf16x2 tv = {v0[j], v1[j]};
        *(bf16x2*)&Vts[0][(vd0 + j) * 64 + pp * 8 + (vkey & 7)] = tv;
    }
    v0 = *(const bf16x8*)(vsec + (size_t)(64 + vkey) * rs + vd0);
    v1 = *(const bf16x8*)(vsec + (size_t)(64 + vkey + 1) * rs + vd0);
    LGKM0();
    SB(); MEMF();

    for (int kt = 0; kt < SEQ; kt += 64) {
        const int tpar = (kt >> 6) & 1;
        bf16* Kc = Ksm[tpar];
        bf16* Kn = Ksm[tpar ^ 1];
        const bf16* Vc = Vts[tpar];
        bf16*       Vn = Vts[tpar ^ 1];

        // issue next tile's K staging first (max latency slack)
        if (kt + 64 < SEQ) stageK(kt + 64, Kn);

        // V(t+1) regs -> Vts[tpar^1] (XOR-swizzled); prefetch V(t+2) regs.
        if (kt + 64 < SEQ) {
#pragma unroll
            for (int j = 0; j < 8; j++) {
                int pp = (vkey >> 3) ^ j;
                bf16x2 tv = {v0[j], v1[j]};
                *(bf16x2*)&Vn[(vd0 + j) * 64 + pp * 8 + (vkey & 7)] = tv;
            }
            if (kt + 128 < SEQ) {
                v0 = *(const bf16x8*)(vsec + (size_t)(kt + 128 + vkey) * rs + vd0);
                v1 = *(const bf16x8*)(vsec + (size_t)(kt + 128 + vkey + 1) * rs + vd0);
            }
        }

        // K fragments: read ONCE per wave-tile, reused across 4 qm
        bf16x8 kf[4][2];
#pragma unroll
        for (int kn = 0; kn < 4; kn++) {
            int row = kn * 16 + q;
            kf[kn][0] = *(const bf16x8*)&Kc[row * 64 + ((g    ) ^ l7) * 8];
            kf[kn][1] = *(const bf16x8*)&Kc[row * 64 + ((4 + g) ^ l7) * 8];
        }

        // QK^T per qm (keeps s live range short), exp2-domain, write P to LDS
#pragma unroll
        for (int qm = 0; qm < 4; qm++) {
            f32x4 s[4];
#pragma unroll
            for (int kn = 0; kn < 4; kn++) s[kn] = (f32x4){0.f, 0.f, 0.f, 0.f};
            __builtin_amdgcn_s_setprio(1);
#pragma unroll
            for (int kn = 0; kn < 4; kn++) {
                s[kn] = __builtin_amdgcn_mfma_f32_16x16x32_bf16(kf[kn][0], qf[qm][0], s[kn], 0, 0, 0);
                s[kn] = __builtin_amdgcn_mfma_f32_16x16x32_bf16(kf[kn][1], qf[qm][1], s[kn], 0, 0, 0);
            }
            __builtin_amdgcn_s_setprio(0);
#pragma unroll
            for (int kn = 0; kn < 4; kn++) {
                float p0 = EXP2F(s[kn][0]);
                float p1 = EXP2F(s[kn][1]);
                float p2 = EXP2F(s[kn][2]);
                float p3 = EXP2F(s[kn][3]);
                bf16x4 pk = {(bf16)p0, (bf16)p1, (bf16)p2, (bf16)p3};
                int pslot = (2 * kn + (g >> 1)) ^ l7;
                *(bf16x4*)&Pw[(qm * 16 + q) * 64 + pslot * 8 + (g & 1) * 4] = pk;
            }
        }

        // P fragments (per-wave region, in-order DS pipe -> compiler waits at use)
        bf16x8 pf[4][2];
#pragma unroll
        for (int qm = 0; qm < 4; qm++)
#pragma unroll
            for (int ks = 0; ks < 2; ks++)
                pf[qm][ks] = *(const bf16x8*)&Pw[(qm * 16 + q) * 64 + ((ks * 4 + g) ^ l7) * 8];

        // PV + lsum from Vc (written tile t-1, barrier-separated); no mid barrier
        __builtin_amdgcn_s_setprio(1);
#pragma unroll
        for (int qm = 0; qm < 4; qm++) {
            acc_l[qm] = __builtin_amdgcn_mfma_f32_16x16x32_bf16(pf[qm][0], onesf, acc_l[qm], 0, 0, 0);
            acc_l[qm] = __builtin_amdgcn_mfma_f32_16x16x32_bf16(pf[qm][1], onesf, acc_l[qm], 0, 0, 0);
        }
#pragma unroll
        for (int dn = 0; dn < 4; dn++) {
            int vrow = dn * 16 + q;
            bf16x8 vf0 = *(const bf16x8*)&Vc[vrow * 64 + ((g    ) ^ l7) * 8];
            bf16x8 vf1 = *(const bf16x8*)&Vc[vrow * 64 + ((4 + g) ^ l7) * 8];
#pragma unroll
            for (int qm = 0; qm < 4; qm++) {
                acc[qm][dn] = __builtin_amdgcn_mfma_f32_16x16x32_bf16(pf[qm][0], vf0, acc[qm][dn], 0, 0, 0);
                acc[qm][dn] = __builtin_amdgcn_mfma_f32_16x16x32_bf16(pf[qm][1], vf1, acc[qm][dn], 0, 0, 0);
            }
        }
        __builtin_amdgcn_s_setprio(0);

        // single tile-end drain+barrier
        LGKM0();
        VMCNT0();
        SB(); MEMF();
    }

    // epilogue: O / lsum — acc_l already in the same (q = g*4+j) layout
#pragma unroll
    for (int qm = 0; qm < 4; qm++) {
        float rl[4];
#pragma unroll
        for (int j = 0; j < 4; j++) rl[j] = RCPF(acc_l[qm][j]);
#pragma unroll
        for (int dn = 0; dn < 4; dn++) {
            int gcol = hh * 64 + dn * 16 + q;
#pragma unroll
            for (int j = 0; j < 4; j++) {
                int grow = qb * 256 + wid * 64 + qm * 16 + g * 4 + j;
                attnout[(size_t)(b * SEQ + grow) * DM + gcol] = (bf16)(acc[qm][dn][j] * rl[j]);
            }
        }
    }
}

// ---------------- launch ----------------
extern "C" void kernel_launch(void* const* d_in, const int* in_sizes, int n_in,
                              void* d_out, int out_size, void* d_ws, size_t ws_size,
                              hipStream_t stream)
{
    const float* x     = (const float*)d_in[0];
    const float* qkv_w = (const float*)d_in[1];
    const float* qkv_b = (const float*)d_in[2];
    const float* out_w = (const float*)d_in[3];
    const float* out_b = (const float*)d_in[4];
    float* out = (float*)d_out;

    char* ws = (char*)d_ws;
    const size_t off_xb   = 0;
    const size_t off_wqkv = off_xb   + 16777216;
    const size_t off_wout = off_wqkv + 6291456;
    const size_t off_qkv  = off_wout + 2097152;
    const size_t off_attn = off_qkv  + 50331648;
    bf16* xb   = (bf16*)(ws + off_xb);
    bf16* wqkv = (bf16*)(ws + off_wqkv);
    bf16* wout = (bf16*)(ws + off_wout);
    bf16* qkvb = (bf16*)(ws + off_qkv);
    bf16* attn = (bf16*)(ws + off_attn);

    static bool attr_done = false;
    if (!attr_done) {
        (void)hipFuncSetAttribute((const void*)gemm1_384,
                                  hipFuncAttributeMaxDynamicSharedMemorySize, 163840);
        (void)hipFuncSetAttribute((const void*)gemm8p_kernel<4, 0>,
                                  hipFuncAttributeMaxDynamicSharedMemorySize, 98304);
        attr_done = true;
    }

    cvt3_kernel<<<1408, 256, 0, stream>>>(x, xb, qkv_w, wqkv, out_w, wout);

    // GEMM1: 8192x3072x1024, 256x384 tiles -> grid 8x32 = 256 blocks = 1/CU, no tail
    gemm1_384<<<dim3(QKV_N / 384, M_TOT / 256), 512, 163840, stream>>>(
        xb, wqkv, qkv_b, qkvb, M_TOT, QKV_N, DM);

    // attn: 512 blocks (2/CU), qm=4, single-barrier tiles (R11-verified best)
    attn_kernel<<<dim3(SEQ / 256, BATCH * NH), 256, 0, stream>>>(qkvb, attn);

    // GEMM2: 8192x1024x1024, BM=128 -> grid 4x64 = 256 blocks (1/CU, balanced)
    gemm8p_kernel<4, 0><<<dim3(DM / 256, M_TOT / 128), 512, 98304, stream>>>(
        attn, wout, out_b, (void*)out, M_TOT, DM, DM);
}

// Round 14
// 174.718 us; speedup vs baseline: 1.2003x; 1.2003x over previous
//
#include <hip/hip_runtime.h>
#include <hip/hip_bf16.h>
#include <stdint.h>

typedef __bf16 bf16;
typedef __bf16 bf16x2 __attribute__((ext_vector_type(2)));
typedef __bf16 bf16x4 __attribute__((ext_vector_type(4)));
typedef __bf16 bf16x8 __attribute__((ext_vector_type(8)));
typedef float  f32x4  __attribute__((ext_vector_type(4)));

#define BATCH 4
#define SEQ 2048
#define DM 1024
#define NH 16
#define HD 64
#define M_TOT (BATCH*SEQ)   // 8192
#define QKV_N (3*DM)        // 3072

#if __has_builtin(__builtin_amdgcn_exp2f)
#define EXP2F(x) __builtin_amdgcn_exp2f(x)
#else
#define EXP2F(x) exp2f(x)
#endif
#if __has_builtin(__builtin_amdgcn_rcpf)
#define RCPF(x) __builtin_amdgcn_rcpf(x)
#else
#define RCPF(x) (1.0f/(x))
#endif

__device__ __forceinline__ void gld_lds16(const bf16* g, bf16* l) {
    __builtin_amdgcn_global_load_lds(
        (const __attribute__((address_space(1))) void*)g,
        (__attribute__((address_space(3))) void*)l, 16, 0, 0);
}

// ---------------- fused fp32 -> bf16 converts (one launch) ----------------
__device__ __forceinline__ void cvt_seg(const float* __restrict__ src,
                                        bf16* __restrict__ dst,
                                        int n, int tid0, int nthreads) {
    for (int idx = tid0 * 8; idx < n; idx += nthreads * 8) {
        float4 a = *(const float4*)(src + idx);
        float4 b = *(const float4*)(src + idx + 4);
        bf16x8 o;
        o[0] = (bf16)a.x; o[1] = (bf16)a.y; o[2] = (bf16)a.z; o[3] = (bf16)a.w;
        o[4] = (bf16)b.x; o[5] = (bf16)b.y; o[6] = (bf16)b.z; o[7] = (bf16)b.w;
        *(bf16x8*)(dst + idx) = o;
    }
}

__global__ void cvt3_kernel(const float* __restrict__ x, bf16* __restrict__ xb,
                            const float* __restrict__ w1, bf16* __restrict__ w1b,
                            const float* __restrict__ w2, bf16* __restrict__ w2b) {
    int bid = blockIdx.x, tid = threadIdx.x;
    if (bid < 1024)       cvt_seg(x,  xb,  M_TOT * DM,  bid * 256 + tid,          1024 * 256);
    else if (bid < 1280)  cvt_seg(w1, w1b, QKV_N * DM, (bid - 1024) * 256 + tid,  256 * 256);
    else                  cvt_seg(w2, w2b, DM * DM,    (bid - 1280) * 256 + tid,  128 * 256);
}

// ---------------- 8-phase GEMM: C[M,N] = A[M,K] * B[N,K]^T + bias ----------------
// R2/R5/R11-verified best configs: GEMM1 MREP=8 (BM=256, 384 blocks), GEMM2 MREP=4.
// Grid/tile experiments R4 (MREP=4 GEMM1), R8 (256x128), R12/R13 (256x384,
// register-infeasible: 192-reg acc spilled at VGPR cap 128 -> 174MB scratch)
// all regressed; this config is LOCKED.
#define SB()    __builtin_amdgcn_s_barrier()
#define MEMF()  asm volatile("" ::: "memory")
#define LGKM0() asm volatile("s_waitcnt lgkmcnt(0)" ::: "memory")
#define VMCNT0() asm volatile("s_waitcnt vmcnt(0)" ::: "memory")
#define FRAG(buf, row, ks) (*(const bf16x8*)&(buf)[(int)(row) * 64 + ((((ks) << 2) + g) ^ l7) * 8])

template<int MREP, int BF16_OUT>
__global__ __launch_bounds__(512, 2) void gemm8p_kernel(
    const bf16* __restrict__ A, const bf16* __restrict__ B,
    const float* __restrict__ bias, void* __restrict__ Cv,
    int M, int N, int K)
{
    constexpr int BM = MREP * 32;     // 256 or 128
    constexpr int AH = MREP / 2;      // frag-rows per A read phase
    extern __shared__ __align__(16) bf16 lds[];
    bf16* As = lds;                   // [2][BM][64]
    bf16* Bs = lds + 2 * BM * 64;     // [2][256][64]

    const int tid = threadIdx.x, wid = tid >> 6, lane = tid & 63;
    const int q = lane & 15, g = lane >> 4, l7 = lane & 7;
    const int wr = wid >> 2, wcn = wid & 3;

    const int ntx = N >> 8;
    const int nwg = gridDim.x * gridDim.y;
    const int bid = blockIdx.x + blockIdx.y * gridDim.x;
    const int wgid = (bid & 7) * (nwg >> 3) + (bid >> 3);   // grids are %8==0
    const size_t rowbase = (size_t)(wgid / ntx) * BM;
    const size_t colbase = (size_t)(wgid % ntx) * 256;
    const int NT = K >> 6;
    const int rA = wr * (MREP * 16);
    const int rB = wcn * 64;

    const bf16* Asrc = A + rowbase * K;
    const bf16* Bsrc = B + colbase * K;

    auto stage = [&](const bf16* src, bf16* dst) {
#pragma unroll
        for (int i = 0; i < 2; i++) {
            const int chunk = i * 8 + wid;            // 0..15, 8 rows each
            const int row = chunk * 8 + (lane >> 3);  // 0..127
            const int cg = (lane & 7) ^ (row & 7);
            gld_lds16(src + (size_t)row * K + cg * 8, dst + chunk * 512);
        }
    };

    // ---------------- prologue: tile0 (A+B) and tile1 (B halves) ----------------
    stage(Bsrc, Bs);                                         // B-h0(0)
    stage(Bsrc + 128 * (size_t)K, Bs + 8192);                // B-h1(0)
    stage(Asrc, As);                                         // A-h0(0)
    if (MREP == 8) stage(Asrc + 128 * (size_t)K, As + 8192); // A-h1(0)
    if (NT > 1) {
        stage(Bsrc + 64, Bs + 16384);                        // B-h0(1) -> buf1
        stage(Bsrc + 128 * (size_t)K + 64, Bs + 16384 + 8192);
        asm volatile("s_waitcnt vmcnt(4)" ::: "memory");     // tile0 complete
    } else {
        VMCNT0();
    }
    SB(); MEMF();

    f32x4 acc[MREP][4];
#pragma unroll
    for (int i = 0; i < MREP; i++)
#pragma unroll
        for (int n = 0; n < 4; n++) acc[i][n] = (f32x4){0.f, 0.f, 0.f, 0.f};

    bf16x8 af[AH][2], bfr[4][2];

    for (int t = 0; t < NT; t++) {
        const int p = t & 1;
        const bf16* Ap = As + p * (BM * 64);
        const bf16* Bp = Bs + p * 16384;
        bf16* An  = As + (p ^ 1) * (BM * 64);   // A dest for tile t+1
        bf16* Bn2 = Bs + p * 16384;             // B dest for tile t+2 (same parity)

        // ---------- P0: read A-half0 + B ni0-1; stage A-h0(t+1) ----------
        if (t + 1 < NT) stage(Asrc + (size_t)(t + 1) * 64, An);
#pragma unroll
        for (int i = 0; i < AH; i++) {
            const int row = rA + i * 16 + q;
#pragma unroll
            for (int ks = 0; ks < 2; ks++) af[i][ks] = FRAG(Ap, row, ks);
        }
#pragma unroll
        for (int n = 0; n < 2; n++) {
            const int row = rB + n * 16 + q;
#pragma unroll
            for (int ks = 0; ks < 2; ks++) bfr[n][ks] = FRAG(Bp, row, ks);
        }
        SB(); LGKM0();
        __builtin_amdgcn_s_setprio(1);
#pragma unroll
        for (int i = 0; i < AH; i++)
#pragma unroll
            for (int n = 0; n < 2; n++)
#pragma unroll
                for (int ks = 0; ks < 2; ks++)
                    acc[i][n] = __builtin_amdgcn_mfma_f32_16x16x32_bf16(af[i][ks], bfr[n][ks], acc[i][n], 0, 0, 0);
        __builtin_amdgcn_s_setprio(0);
        SB(); MEMF();

        // ---------- P1: read B ni2-3; stage A-h1(t+1) ----------
        if (MREP == 8 && t + 1 < NT)
            stage(Asrc + 128 * (size_t)K + (size_t)(t + 1) * 64, An + 8192);
#pragma unroll
        for (int n = 2; n < 4; n++) {
            const int row = rB + n * 16 + q;
#pragma unroll
            for (int ks = 0; ks < 2; ks++) bfr[n][ks] = FRAG(Bp, row, ks);
        }
        SB(); LGKM0();
        __builtin_amdgcn_s_setprio(1);
#pragma unroll
        for (int i = 0; i < AH; i++)
#pragma unroll
            for (int n = 2; n < 4; n++)
#pragma unroll
                for (int ks = 0; ks < 2; ks++)
                    acc[i][n] = __builtin_amdgcn_mfma_f32_16x16x32_bf16(af[i][ks], bfr[n][ks], acc[i][n], 0, 0, 0);
        __builtin_amdgcn_s_setprio(0);
        SB(); MEMF();

        // ---------- P2: read A-half1; stage B-h0(t+2) ----------
        if (t + 2 < NT) stage(Bsrc + (size_t)(t + 2) * 64, Bn2);
#pragma unroll
        for (int i = 0; i < AH; i++) {
            const int row = rA + (AH + i) * 16 + q;
#pragma unroll
            for (int ks = 0; ks < 2; ks++) af[i][ks] = FRAG(Ap, row, ks);
        }
        SB(); LGKM0();
        __builtin_amdgcn_s_setprio(1);
#pragma unroll
        for (int i = 0; i < AH; i++)
#pragma unroll
            for (int n = 2; n < 4; n++)
#pragma unroll
                for (int ks = 0; ks < 2; ks++)
                    acc[AH + i][n] = __builtin_amdgcn_mfma_f32_16x16x32_bf16(af[i][ks], bfr[n][ks], acc[AH + i][n], 0, 0, 0);
        __builtin_amdgcn_s_setprio(0);
        SB(); MEMF();

        // ---------- P3: no reads; stage B-h1(t+2); counted vmcnt ----------
        if (t + 2 < NT)
            stage(Bsrc + 128 * (size_t)K + (size_t)(t + 2) * 64, Bn2 + 8192);
        SB(); LGKM0();
        __builtin_amdgcn_s_setprio(1);
#pragma unroll
        for (int i = 0; i < AH; i++)
#pragma unroll
            for (int n = 0; n < 2; n++)
#pragma unroll
                for (int ks = 0; ks < 2; ks++)
                    acc[AH + i][n] = __builtin_amdgcn_mfma_f32_16x16x32_bf16(af[i][ks], bfr[n][ks], acc[AH + i][n], 0, 0, 0);
        __builtin_amdgcn_s_setprio(0);
        if (t + 2 < NT) { asm volatile("s_waitcnt vmcnt(4)" ::: "memory"); }
        else            { VMCNT0(); }
        SB(); MEMF();
    }

    // ---------------- epilogue ----------------
    float bv[4];
#pragma unroll
    for (int n = 0; n < 4; n++) bv[n] = bias[colbase + rB + n * 16 + q];
#pragma unroll
    for (int mi = 0; mi < MREP; mi++) {
#pragma unroll
        for (int n = 0; n < 4; n++) {
            const size_t col = colbase + rB + n * 16 + q;
#pragma unroll
            for (int j = 0; j < 4; j++) {
                const size_t row = rowbase + rA + mi * 16 + g * 4 + j;
                float v = acc[mi][n][j] + bv[n];
                if (BF16_OUT) ((bf16*)Cv)[row * N + col] = (bf16)v;
                else          ((float*)Cv)[row * N + col] = v;
            }
        }
    }
}

// ---------------- Flash attention v10 (R11-verified best: 85.8-86.4us) --------
// R5 Psm path + V-dbuf, ONE barrier per tile.
__global__ __launch_bounds__(256, 2) void attn_kernel(
    const bf16* __restrict__ qkv, bf16* __restrict__ attnout)
{
    __shared__ __align__(16) bf16 Ksm[2][64 * 64];
    __shared__ __align__(16) bf16 Vts[2][64 * 64];
    __shared__ __align__(16) bf16 Psm[4 * 64 * 64];

    const int tid = threadIdx.x, wid = tid >> 6, lane = tid & 63;
    const int g = lane >> 4, q = lane & 15, l7 = lane & 7;

    // bijective XCD swizzle: each XCD owns 8 consecutive bh (KV fits its L2)
    const int bid = blockIdx.x + blockIdx.y * gridDim.x;   // 0..511
    const int xcd = bid & 7, idx = bid >> 3;               // idx 0..63
    const int bh = xcd * 8 + (idx >> 3);
    const int qb = idx & 7;                                // 8 q-blocks of 256 rows
    const int b = bh >> 4, hh = bh & 15;

    const size_t rs = QKV_N;
    const bf16* qsec = qkv + (size_t)(b * SEQ) * rs + hh * 64;
    const bf16* ksec = qsec + DM;
    const bf16* vsec = qsec + 2 * DM;

    const float SC2 = 0.18033688011112042f;   // 0.125 * log2(e)

    // Q fragments pre-scaled into exp2 domain: 4 x 16 rows per wave
    bf16x8 qf[4][2];   // [qm][ks]
#pragma unroll
    for (int qm = 0; qm < 4; qm++) {
        int qrow = qb * 256 + wid * 64 + qm * 16 + q;
#pragma unroll
        for (int ks = 0; ks < 2; ks++) {
            bf16x8 raw = *(const bf16x8*)(qsec + (size_t)qrow * rs + ks * 32 + g * 8);
            bf16x8 sc;
#pragma unroll
            for (int j = 0; j < 8; j++) sc[j] = (bf16)((float)raw[j] * SC2);
            qf[qm][ks] = sc;
        }
    }

    bf16x8 onesf;
#pragma unroll
    for (int j = 0; j < 8; j++) onesf[j] = (bf16)1.0f;

    f32x4 acc[4][4];
    f32x4 acc_l[4];
#pragma unroll
    for (int qm = 0; qm < 4; qm++) {
        acc_l[qm] = (f32x4){0.f, 0.f, 0.f, 0.f};
#pragma unroll
        for (int dn = 0; dn < 4; dn++) acc[qm][dn] = (f32x4){0.f, 0.f, 0.f, 0.f};
    }
    bf16* Pw = &Psm[wid * 64 * 64];

    // V staging task: 2 keys x 8 d per thread
    const int vkey = 2 * (tid & 31);
    const int vd0 = (tid >> 5) * 8;

    // K tile staging: async global->LDS, source pre-swizzled (LDS-only lambda)
    auto stageK = [&](int kt, bf16* dst) {
#pragma unroll
        for (int r = 0; r < 2; r++) {
            int row = r * 32 + wid * 8 + (lane >> 3);
            int cbs = (lane & 7) ^ (row & 7);
            gld_lds16(ksec + (size_t)(kt + row) * rs + cbs * 8,
                      dst + (r * 32 + wid * 8) * 64);
        }
    };

    // ---------------- prologue: K(0)->Ksm[0], V(0)->Vts[0], V(1)->regs --------
    stageK(0, Ksm[0]);
    bf16x8 v0 = *(const bf16x8*)(vsec + (size_t)vkey * rs + vd0);
    bf16x8 v1 = *(const bf16x8*)(vsec + (size_t)(vkey + 1) * rs + vd0);
    VMCNT0();                       // K(0) in LDS, V(0) in regs
#pragma unroll
    for (int j = 0; j < 8; j++) {
        int pp = (vkey >> 3) ^ j;
        bf16x2 tv = {v0[j], v1[j]};
        *(bf16x2*)&Vts[0][(vd0 + j) * 64 + pp * 8 + (vkey & 7)] = tv;
    }
    v0 = *(const bf16x8*)(vsec + (size_t)(64 + vkey) * rs + vd0);
    v1 = *(const bf16x8*)(vsec + (size_t)(64 + vkey + 1) * rs + vd0);
    LGKM0();
    SB(); MEMF();

    for (int kt = 0; kt < SEQ; kt += 64) {
        const int tpar = (kt >> 6) & 1;
        bf16* Kc = Ksm[tpar];
        bf16* Kn = Ksm[tpar ^ 1];
        const bf16* Vc = Vts[tpar];
        bf16*       Vn = Vts[tpar ^ 1];

        // issue next tile's K staging first (max latency slack)
        if (kt + 64 < SEQ) stageK(kt + 64, Kn);

        // V(t+1) regs -> Vts[tpar^1] (XOR-swizzled); prefetch V(t+2) regs.
        if (kt + 64 < SEQ) {
#pragma unroll
            for (int j = 0; j < 8; j++) {
                int pp = (vkey >> 3) ^ j;
                bf16x2 tv = {v0[j], v1[j]};
                *(bf16x2*)&Vn[(vd0 + j) * 64 + pp * 8 + (vkey & 7)] = tv;
            }
            if (kt + 128 < SEQ) {
                v0 = *(const bf16x8*)(vsec + (size_t)(kt + 128 + vkey) * rs + vd0);
                v1 = *(const bf16x8*)(vsec + (size_t)(kt + 128 + vkey + 1) * rs + vd0);
            }
        }

        // K fragments: read ONCE per wave-tile, reused across 4 qm
        bf16x8 kf[4][2];
#pragma unroll
        for (int kn = 0; kn < 4; kn++) {
            int row = kn * 16 + q;
            kf[kn][0] = *(const bf16x8*)&Kc[row * 64 + ((g    ) ^ l7) * 8];
            kf[kn][1] = *(const bf16x8*)&Kc[row * 64 + ((4 + g) ^ l7) * 8];
        }

        // QK^T per qm (keeps s live range short), exp2-domain, write P to LDS
#pragma unroll
        for (int qm = 0; qm < 4; qm++) {
            f32x4 s[4];
#pragma unroll
            for (int kn = 0; kn < 4; kn++) s[kn] = (f32x4){0.f, 0.f, 0.f, 0.f};
            __builtin_amdgcn_s_setprio(1);
#pragma unroll
            for (int kn = 0; kn < 4; kn++) {
                s[kn] = __builtin_amdgcn_mfma_f32_16x16x32_bf16(kf[kn][0], qf[qm][0], s[kn], 0, 0, 0);
                s[kn] = __builtin_amdgcn_mfma_f32_16x16x32_bf16(kf[kn][1], qf[qm][1], s[kn], 0, 0, 0);
            }
            __builtin_amdgcn_s_setprio(0);
#pragma unroll
            for (int kn = 0; kn < 4; kn++) {
                float p0 = EXP2F(s[kn][0]);
                float p1 = EXP2F(s[kn][1]);
                float p2 = EXP2F(s[kn][2]);
                float p3 = EXP2F(s[kn][3]);
                bf16x4 pk = {(bf16)p0, (bf16)p1, (bf16)p2, (bf16)p3};
                int pslot = (2 * kn + (g >> 1)) ^ l7;
                *(bf16x4*)&Pw[(qm * 16 + q) * 64 + pslot * 8 + (g & 1) * 4] = pk;
            }
        }

        // P fragments (per-wave region, in-order DS pipe -> compiler waits at use)
        bf16x8 pf[4][2];
#pragma unroll
        for (int qm = 0; qm < 4; qm++)
#pragma unroll
            for (int ks = 0; ks < 2; ks++)
                pf[qm][ks] = *(const bf16x8*)&Pw[(qm * 16 + q) * 64 + ((ks * 4 + g) ^ l7) * 8];

        // PV + lsum from Vc (written tile t-1, barrier-separated); no mid barrier
        __builtin_amdgcn_s_setprio(1);
#pragma unroll
        for (int qm = 0; qm < 4; qm++) {
            acc_l[qm] = __builtin_amdgcn_mfma_f32_16x16x32_bf16(pf[qm][0], onesf, acc_l[qm], 0, 0, 0);
            acc_l[qm] = __builtin_amdgcn_mfma_f32_16x16x32_bf16(pf[qm][1], onesf, acc_l[qm], 0, 0, 0);
        }
#pragma unroll
        for (int dn = 0; dn < 4; dn++) {
            int vrow = dn * 16 + q;
            bf16x8 vf0 = *(const bf16x8*)&Vc[vrow * 64 + ((g    ) ^ l7) * 8];
            bf16x8 vf1 = *(const bf16x8*)&Vc[vrow * 64 + ((4 + g) ^ l7) * 8];
#pragma unroll
            for (int qm = 0; qm < 4; qm++) {
                acc[qm][dn] = __builtin_amdgcn_mfma_f32_16x16x32_bf16(pf[qm][0], vf0, acc[qm][dn], 0, 0, 0);
                acc[qm][dn] = __builtin_amdgcn_mfma_f32_16x16x32_bf16(pf[qm][1], vf1, acc[qm][dn], 0, 0, 0);
            }
        }
        __builtin_amdgcn_s_setprio(0);

        // single tile-end drain+barrier
        LGKM0();
        VMCNT0();
        SB(); MEMF();
    }

    // epilogue: O / lsum — acc_l already in the same (q = g*4+j) layout
#pragma unroll
    for (int qm = 0; qm < 4; qm++) {
        float rl[4];
#pragma unroll
        for (int j = 0; j < 4; j++) rl[j] = RCPF(acc_l[qm][j]);
#pragma unroll
        for (int dn = 0; dn < 4; dn++) {
            int gcol = hh * 64 + dn * 16 + q;
#pragma unroll
            for (int j = 0; j < 4; j++) {
                int grow = qb * 256 + wid * 64 + qm * 16 + g * 4 + j;
                attnout[(size_t)(b * SEQ + grow) * DM + gcol] = (bf16)(acc[qm][dn][j] * rl[j]);
            }
        }
    }
}

// ---------------- launch ----------------
extern "C" void kernel_launch(void* const* d_in, const int* in_sizes, int n_in,
                              void* d_out, int out_size, void* d_ws, size_t ws_size,
                              hipStream_t stream)
{
    const float* x     = (const float*)d_in[0];
    const float* qkv_w = (const float*)d_in[1];
    const float* qkv_b = (const float*)d_in[2];
    const float* out_w = (const float*)d_in[3];
    const float* out_b = (const float*)d_in[4];
    float* out = (float*)d_out;

    char* ws = (char*)d_ws;
    const size_t off_xb   = 0;
    const size_t off_wqkv = off_xb   + 16777216;
    const size_t off_wout = off_wqkv + 6291456;
    const size_t off_qkv  = off_wout + 2097152;
    const size_t off_attn = off_qkv  + 50331648;
    bf16* xb   = (bf16*)(ws + off_xb);
    bf16* wqkv = (bf16*)(ws + off_wqkv);
    bf16* wout = (bf16*)(ws + off_wout);
    bf16* qkvb = (bf16*)(ws + off_qkv);
    bf16* attn = (bf16*)(ws + off_attn);

    static bool attr_done = false;
    if (!attr_done) {
        (void)hipFuncSetAttribute((const void*)gemm8p_kernel<8, 1>,
                                  hipFuncAttributeMaxDynamicSharedMemorySize, 131072);
        (void)hipFuncSetAttribute((const void*)gemm8p_kernel<4, 0>,
                                  hipFuncAttributeMaxDynamicSharedMemorySize, 98304);
        attr_done = true;
    }

    cvt3_kernel<<<1408, 256, 0, stream>>>(x, xb, qkv_w, wqkv, out_w, wout);

    // GEMM1: 8192x3072x1024, BM=256 -> grid 12x32 = 384 blocks (R2/R5/R11-verified best)
    gemm8p_kernel<8, 1><<<dim3(QKV_N / 256, M_TOT / 256), 512, 131072, stream>>>(
        xb, wqkv, qkv_b, (void*)qkvb, M_TOT, QKV_N, DM);

    // attn: 512 blocks (2/CU), qm=4, single-barrier tiles (R11-verified best)
    attn_kernel<<<dim3(SEQ / 256, BATCH * NH), 256, 0, stream>>>(qkvb, attn);

    // GEMM2: 8192x1024x1024, BM=128 -> grid 4x64 = 256 blocks (1/CU, balanced)
    gemm8p_kernel<4, 0><<<dim3(DM / 256, M_TOT / 128), 512, 98304, stream>>>(
        attn, wout, out_b, (void*)out, M_TOT, DM, DM);
}